// Round 6
// baseline (465.593 us; speedup 1.0000x reference)
//
#include <hip/hip_runtime.h>

#define NS 4096
#define NT 8192
#define DIN 256
#define DOUT 128

// float offsets into workspace
#define OFF_RS   0                       // deg_so then rs in place [NS]
#define OFF_RT   (NS)                    // deg_to then rt in place [NT]
#define OFF_C1   (OFF_RT + NT)           // 12288
#define OFF_C2   (OFF_C1 + NS*DOUT)      // 536576
#define OFF_XS   (OFF_C2 + NT*DOUT)      // 1585152
#define OFF_YS   (OFF_XS + NS*DOUT)
#define OFF_XNS  (OFF_YS + NT*DOUT)

typedef __attribute__((ext_vector_type(8))) short bf8v;
typedef __attribute__((ext_vector_type(4))) float f32x4;

__device__ __forceinline__ ushort f2bf(float f) {
    // exact round-to-nearest-even fp32 -> bf16 (finite inputs only)
    unsigned x = __float_as_uint(f);
    unsigned r = (x + 0x7fffu + ((x >> 16) & 1u)) >> 16;
    return (ushort)r;
}

__global__ void zero_kernel(float* __restrict__ p, int n4) {
    int i = blockIdx.x * blockDim.x + threadIdx.x;
    int stride = gridDim.x * blockDim.x;
    float4* p4 = (float4*)p;
    float4 z = make_float4(0.f, 0.f, 0.f, 0.f);
    for (; i < n4; i += stride) p4[i] = z;
}

// One pass over adj: row partial sums -> deg_s (atomic), col partials -> deg_t (atomic)
__global__ __launch_bounds__(256)
void adj_deg_kernel(const float* __restrict__ adj,
                    float* __restrict__ deg_s, float* __restrict__ deg_t) {
    const int tid = threadIdx.x;
    const int lane = tid & 63;
    const int c4 = blockIdx.x * 256 + tid;          // float4 column
    const int r0 = blockIdx.y * 32;
    const float4* A4 = (const float4*)adj + (size_t)r0 * (NT / 4) + c4;
    float sx = 0.f, sy = 0.f, sz = 0.f, sw = 0.f;
#pragma unroll 8
    for (int r = 0; r < 32; ++r) {
        float4 v = A4[(size_t)r * (NT / 4)];
        sx += v.x; sy += v.y; sz += v.z; sw += v.w;
        float rp = v.x + v.y + v.z + v.w;
#pragma unroll
        for (int off = 32; off > 0; off >>= 1) rp += __shfl_down(rp, off, 64);
        if (lane == 0) unsafeAtomicAdd(deg_s + r0 + r, rp);
    }
    float* d = deg_t + c4 * 4;
    unsafeAtomicAdd(d + 0, sx);
    unsafeAtomicAdd(d + 1, sy);
    unsafeAtomicAdd(d + 2, sz);
    unsafeAtomicAdd(d + 3, sw);
}

// adj_s row sums -> deg_s (atomic); one wave per row
__global__ __launch_bounds__(256)
void rowsum_s_kernel(const float* __restrict__ adj_s, float* __restrict__ deg_s) {
    const int wid = threadIdx.x >> 6;
    const int lane = threadIdx.x & 63;
    const int row = blockIdx.x * 4 + wid;
    const float4* b = (const float4*)(adj_s + (size_t)row * NS);
    float sum = 0.f;
#pragma unroll 8
    for (int c = lane; c < NS / 4; c += 64) { float4 v = b[c]; sum += v.x + v.y + v.z + v.w; }
#pragma unroll
    for (int off = 32; off > 0; off >>= 1) sum += __shfl_down(sum, off, 64);
    if (lane == 0) unsafeAtomicAdd(deg_s + row, sum);
}

// adj_t col partial sums -> deg_t (atomic); 64 rows per block
__global__ __launch_bounds__(256)
void colsum_t_kernel(const float* __restrict__ A, float* __restrict__ deg_t) {
    const int c4 = blockIdx.x * 256 + threadIdx.x;
    const int r0 = blockIdx.y * 64;
    const float4* A4 = (const float4*)A + (size_t)r0 * (NT / 4) + c4;
    float sx = 0.f, sy = 0.f, sz = 0.f, sw = 0.f;
#pragma unroll 8
    for (int r = 0; r < 64; ++r) {
        float4 v = A4[(size_t)r * (NT / 4)];
        sx += v.x; sy += v.y; sz += v.z; sw += v.w;
    }
    float* d = deg_t + c4 * 4;
    unsafeAtomicAdd(d + 0, sx);
    unsafeAtomicAdd(d + 1, sy);
    unsafeAtomicAdd(d + 2, sz);
    unsafeAtomicAdd(d + 3, sw);
}

// deg -> sqrt(deg + 1), in place over rs|rt (contiguous 12288)
__global__ void finish_deg_kernel(float* __restrict__ deg) {
    int t = blockIdx.x * blockDim.x + threadIdx.x;
    deg[t] = sqrtf(deg[t] + 1.0f);
}

// out[m, :] = (inp[m, :] @ W) / rdeg[m];  inp [M, 256], W [256, 128]  (fp32 VALU)
__global__ __launch_bounds__(256)
void proj_scale_kernel(const float* __restrict__ inp,
                       const float* __restrict__ W,
                       const float* __restrict__ rdeg,
                       float* __restrict__ outp) {
    __shared__ float As[32][68];
    __shared__ float Bs[32][128];
    const int tid = threadIdx.x;
    const int m0 = blockIdx.x * 64;
    const int tx = tid & 15, ty = tid >> 4;
    const int arow = tid >> 3, acg = tid & 7;
    const int bk = tid >> 5, bng = tid & 31;

    float acc[4][8];
#pragma unroll
    for (int r = 0; r < 4; ++r)
#pragma unroll
        for (int c = 0; c < 8; ++c) acc[r][c] = 0.f;

    for (int kt = 0; kt < DIN; kt += 32) {
        const float* Ab = inp + (size_t)(m0 + arow) * DIN + kt + acg * 4;
        float4 a0 = *(const float4*)Ab;
        float4 a1 = *(const float4*)(Ab + (size_t)32 * DIN);
        const float* Bb = W + (size_t)(kt + bk) * DOUT + bng * 4;
        float4 b0 = *(const float4*)Bb;
        float4 b1 = *(const float4*)(Bb + 8 * DOUT);
        float4 b2 = *(const float4*)(Bb + 16 * DOUT);
        float4 b3 = *(const float4*)(Bb + 24 * DOUT);
        __syncthreads();
        As[acg * 4 + 0][arow] = a0.x;
        As[acg * 4 + 1][arow] = a0.y;
        As[acg * 4 + 2][arow] = a0.z;
        As[acg * 4 + 3][arow] = a0.w;
        As[acg * 4 + 0][arow + 32] = a1.x;
        As[acg * 4 + 1][arow + 32] = a1.y;
        As[acg * 4 + 2][arow + 32] = a1.z;
        As[acg * 4 + 3][arow + 32] = a1.w;
        *(float4*)&Bs[bk][bng * 4] = b0;
        *(float4*)&Bs[bk + 8][bng * 4] = b1;
        *(float4*)&Bs[bk + 16][bng * 4] = b2;
        *(float4*)&Bs[bk + 24][bng * 4] = b3;
        __syncthreads();
#pragma unroll
        for (int k = 0; k < 32; ++k) {
            float4 av = *(const float4*)&As[k][ty * 4];
            float4 bv0 = *(const float4*)&Bs[k][tx * 4];
            float4 bv1 = *(const float4*)&Bs[k][tx * 4 + 64];
            float a[4] = {av.x, av.y, av.z, av.w};
            float b[8] = {bv0.x, bv0.y, bv0.z, bv0.w, bv1.x, bv1.y, bv1.z, bv1.w};
#pragma unroll
            for (int r = 0; r < 4; ++r)
#pragma unroll
                for (int c = 0; c < 8; ++c) acc[r][c] = fmaf(a[r], b[c], acc[r][c]);
        }
    }
#pragma unroll
    for (int r = 0; r < 4; ++r) {
        int row = m0 + ty * 4 + r;
        float rd = rdeg[row];
        float* orow = outp + (size_t)row * DOUT;
#pragma unroll
        for (int c = 0; c < 4; ++c) {
            orow[tx * 4 + c] = acc[r][c] / rd;
            orow[tx * 4 + 64 + c] = acc[r][4 + c] / rd;
        }
    }
}

// C[m0:m0+64, 0:128] += op(A)[m0:m0+64, k0:k0+kchunk] @ B[k0:k0+kchunk, 0:128]
// TRANS=0: op(A)=A row-major pitch lda.  TRANS=1: op(A)=A^T, A[k][m] pitch lda.
// BM=64, BN=128, BK=64; 4 waves, each owns a 32x64 sub-tile.
// fp32 global -> bf16 LDS -> mfma_f32_16x16x32_bf16; fp32 atomics into C (few splits).
template<int TRANS>
__global__ __launch_bounds__(256)
void gemm_mfma_kernel(const float* __restrict__ A, int lda,
                      const float* __restrict__ B,
                      float* __restrict__ C, int kchunk) {
    __shared__ ushort As[64][72];    // [m][k], pitch 144 B
    __shared__ ushort Bs[128][72];   // [n][k] (B transposed)
    const int tid = threadIdx.x;
    const int m0 = blockIdx.x * 64;
    const int k0 = blockIdx.y * kchunk;
    const int lane = tid & 63, wid = tid >> 6;
    const int wm = (wid >> 1) * 32, wn = (wid & 1) * 64;
    const int r16 = lane & 15, kg = lane >> 4;

    const int b_kr = tid >> 3, b_f4 = tid & 7;   // B staging: k-row (0..31, +32), col f4 group
    const int a_r = tid >> 2, a_seg = tid & 3;   // A staging: row (0..63), 16-float segment

    f32x4 acc[2][4];
#pragma unroll
    for (int i = 0; i < 2; ++i)
#pragma unroll
        for (int j = 0; j < 4; ++j) acc[i][j] = (f32x4)(0.f);

    float4 aP[4], bP[8];

    auto load_tiles = [&](int ktb) {
        const float* Bb = B + (size_t)(k0 + ktb + b_kr) * DOUT + b_f4 * 4;
#pragma unroll
        for (int r = 0; r < 2; ++r)
#pragma unroll
            for (int i = 0; i < 4; ++i)
                bP[r * 4 + i] = *(const float4*)(Bb + (size_t)(r * 32) * DOUT + i * 32);
        if (TRANS) {
            // A[k][m]: k-row = a_r, m-cols [a_seg*16, +16)
            const float* Ab = A + (size_t)(k0 + ktb + a_r) * lda + m0 + a_seg * 16;
#pragma unroll
            for (int i = 0; i < 4; ++i) aP[i] = *(const float4*)(Ab + i * 4);
        } else {
            // A[m][k]: m-row = a_r, k-cols [a_seg*16, +16)
            const float* Ab = A + (size_t)(m0 + a_r) * lda + k0 + ktb + a_seg * 16;
#pragma unroll
            for (int i = 0; i < 4; ++i) aP[i] = *(const float4*)(Ab + i * 4);
        }
    };

    auto store_tiles = [&]() {
#pragma unroll
        for (int r = 0; r < 2; ++r)
#pragma unroll
            for (int i = 0; i < 4; ++i) {
                float4 v = bP[r * 4 + i];
                int n = b_f4 * 4 + i * 32;
                int k = b_kr + r * 32;
                Bs[n + 0][k] = f2bf(v.x);
                Bs[n + 1][k] = f2bf(v.y);
                Bs[n + 2][k] = f2bf(v.z);
                Bs[n + 3][k] = f2bf(v.w);
            }
        if (TRANS) {
#pragma unroll
            for (int i = 0; i < 4; ++i) {
                float4 v = aP[i];
                int m = a_seg * 16 + i * 4;
                As[m + 0][a_r] = f2bf(v.x);
                As[m + 1][a_r] = f2bf(v.y);
                As[m + 2][a_r] = f2bf(v.z);
                As[m + 3][a_r] = f2bf(v.w);
            }
        } else {
            bf8v w0, w1;
            w0[0] = (short)f2bf(aP[0].x); w0[1] = (short)f2bf(aP[0].y);
            w0[2] = (short)f2bf(aP[0].z); w0[3] = (short)f2bf(aP[0].w);
            w0[4] = (short)f2bf(aP[1].x); w0[5] = (short)f2bf(aP[1].y);
            w0[6] = (short)f2bf(aP[1].z); w0[7] = (short)f2bf(aP[1].w);
            w1[0] = (short)f2bf(aP[2].x); w1[1] = (short)f2bf(aP[2].y);
            w1[2] = (short)f2bf(aP[2].z); w1[3] = (short)f2bf(aP[2].w);
            w1[4] = (short)f2bf(aP[3].x); w1[5] = (short)f2bf(aP[3].y);
            w1[6] = (short)f2bf(aP[3].z); w1[7] = (short)f2bf(aP[3].w);
            *(bf8v*)&As[a_r][a_seg * 16] = w0;
            *(bf8v*)&As[a_r][a_seg * 16 + 8] = w1;
        }
    };

    load_tiles(0);
    for (int kt = 0; kt < kchunk; kt += 64) {
        __syncthreads();   // prior iteration's LDS reads complete
        store_tiles();
        __syncthreads();
        if (kt + 64 < kchunk) load_tiles(kt + 64);   // overlap with MFMA below
#pragma unroll
        for (int kk = 0; kk < 2; ++kk) {
            bf8v af[2], bfr[4];
#pragma unroll
            for (int f = 0; f < 2; ++f)
                af[f] = *(const bf8v*)&As[wm + f * 16 + r16][kk * 32 + kg * 8];
#pragma unroll
            for (int f = 0; f < 4; ++f)
                bfr[f] = *(const bf8v*)&Bs[wn + f * 16 + r16][kk * 32 + kg * 8];
#pragma unroll
            for (int i = 0; i < 2; ++i)
#pragma unroll
                for (int j = 0; j < 4; ++j)
                    acc[i][j] = __builtin_amdgcn_mfma_f32_16x16x32_bf16(af[i], bfr[j], acc[i][j], 0, 0, 0);
        }
    }

    // epilogue: atomic accumulate (split-K)
    const int crow0 = m0 + wm + kg * 4;
#pragma unroll
    for (int i = 0; i < 2; ++i) {
#pragma unroll
        for (int j = 0; j < 4; ++j) {
            float* base = C + (size_t)(crow0 + i * 16) * DOUT + wn + j * 16 + r16;
            unsafeAtomicAdd(base + 0 * DOUT, acc[i][j][0]);
            unsafeAtomicAdd(base + 1 * DOUT, acc[i][j][1]);
            unsafeAtomicAdd(base + 2 * DOUT, acc[i][j][2]);
            unsafeAtomicAdd(base + 3 * DOUT, acc[i][j][3]);
        }
    }
}

// x_new = relu(xs + C1/rs) -> d_out;  xns = x_new/rs -> ws
__global__ void epilogue1_kernel(const float* __restrict__ C1,
                                 const float* __restrict__ xs,
                                 const float* __restrict__ rs,
                                 float* __restrict__ outx,
                                 float* __restrict__ xns) {
    int idx = blockIdx.x * blockDim.x + threadIdx.x;
    if (idx >= NS * DOUT) return;
    int row = idx >> 7;
    float r = rs[row];
    float v = xs[idx] + C1[idx] / r;
    v = v > 0.f ? v : 0.f;
    outx[idx] = v;
    xns[idx] = v / r;
}

// y_new = relu(ys + C2/rt) -> d_out + NS*DOUT
__global__ void epilogue2_kernel(const float* __restrict__ C2,
                                 const float* __restrict__ ys,
                                 const float* __restrict__ rt,
                                 float* __restrict__ outy) {
    int idx = blockIdx.x * blockDim.x + threadIdx.x;
    if (idx >= NT * DOUT) return;
    int row = idx >> 7;
    float v = ys[idx] + C2[idx] / rt[row];
    v = v > 0.f ? v : 0.f;
    outy[idx] = v;
}

extern "C" void kernel_launch(void* const* d_in, const int* in_sizes, int n_in,
                              void* d_out, int out_size, void* d_ws, size_t ws_size,
                              hipStream_t stream) {
    const float* inp_s = (const float*)d_in[0];
    const float* inp_t = (const float*)d_in[1];
    const float* adj   = (const float*)d_in[2];
    const float* adj_s = (const float*)d_in[3];
    const float* adj_t = (const float*)d_in[4];
    const float* W     = (const float*)d_in[5];
    float* out = (float*)d_out;
    float* ws  = (float*)d_ws;

    float* rs  = ws + OFF_RS;
    float* rt  = ws + OFF_RT;
    float* C1  = ws + OFF_C1;
    float* C2  = ws + OFF_C2;
    float* xs  = ws + OFF_XS;
    float* ys  = ws + OFF_YS;
    float* xns = ws + OFF_XNS;

    // zero deg_s + deg_t + C1 + C2 (contiguous [0, OFF_XS))
    zero_kernel<<<1024, 256, 0, stream>>>(ws, OFF_XS / 4);

    // degrees: one read of adj (fused row+col), one of adj_s, one of adj_t
    adj_deg_kernel<<<dim3(NT / 1024, NS / 32), 256, 0, stream>>>(adj, rs, rt);
    rowsum_s_kernel<<<NS / 4, 256, 0, stream>>>(adj_s, rs);
    colsum_t_kernel<<<dim3(NT / 1024, NT / 64), 256, 0, stream>>>(adj_t, rt);
    finish_deg_kernel<<<(NS + NT) / 256, 256, 0, stream>>>(rs);   // rs|rt contiguous

    // projections, pre-scaled: xs = (inp_s@W)/rs, ys = (inp_t@W)/rt
    proj_scale_kernel<<<NS / 64, 256, 0, stream>>>(inp_s, W, rs, xs);
    proj_scale_kernel<<<NT / 64, 256, 0, stream>>>(inp_t, W, rt, ys);

    // C1 = adj_s@xs + adj@ys   [NS,128]   (bf16 MFMA, minimal split-K)
    gemm_mfma_kernel<0><<<dim3(NS / 64, 4), 256, 0, stream>>>(adj_s, NS, xs, C1, NS / 4);
    gemm_mfma_kernel<0><<<dim3(NS / 64, 4), 256, 0, stream>>>(adj, NT, ys, C1, NT / 4);
    epilogue1_kernel<<<(NS * DOUT) / 256, 256, 0, stream>>>(C1, xs, rs, out, xns);

    // C2 = adj_t@ys + adj^T@xns   [NT,128]
    gemm_mfma_kernel<0><<<dim3(NT / 64, 2), 256, 0, stream>>>(adj_t, NT, ys, C2, NT / 2);
    gemm_mfma_kernel<1><<<dim3(NT / 64, 2), 256, 0, stream>>>(adj, NT, xns, C2, NS / 2);
    epilogue2_kernel<<<(NT * DOUT) / 256, 256, 0, stream>>>(C2, ys, rt, out + NS * DOUT);
}

// Round 7
// 458.205 us; speedup vs baseline: 1.0161x; 1.0161x over previous
//
#include <hip/hip_runtime.h>

#define NS 4096
#define NT 8192
#define DIN 256
#define DOUT 128

// float offsets into workspace
#define OFF_RS   0                       // rs [NS] (written final by rowsum)
#define OFF_RT   (NS)                    // deg_to then rt in place [NT]
#define OFF_C1   (OFF_RT + NT)           // 12288
#define OFF_C2   (OFF_C1 + NS*DOUT)      // 536576
#define OFF_XS   (OFF_C2 + NT*DOUT)      // 1585152
#define OFF_YS   (OFF_XS + NS*DOUT)
#define OFF_XNS  (OFF_YS + NT*DOUT)

typedef __attribute__((ext_vector_type(8))) short bf8v;
typedef __attribute__((ext_vector_type(4))) float f32x4;

__device__ __forceinline__ ushort f2bf(float f) {
    // exact round-to-nearest-even fp32 -> bf16 (finite inputs only)
    unsigned x = __float_as_uint(f);
    unsigned r = (x + 0x7fffu + ((x >> 16) & 1u)) >> 16;
    return (ushort)r;
}

__global__ void zero_kernel(float* __restrict__ p, int n4) {
    int i = blockIdx.x * blockDim.x + threadIdx.x;
    int stride = gridDim.x * blockDim.x;
    float4* p4 = (float4*)p;
    float4 z = make_float4(0.f, 0.f, 0.f, 0.f);
    for (; i < n4; i += stride) p4[i] = z;
}

// rs[row] = sqrt(1 + sum adj[row,:] + sum adj_s[row,:]); one wave per row
__global__ __launch_bounds__(256)
void rowsum_rs_kernel(const float* __restrict__ adj,
                      const float* __restrict__ adj_s,
                      float* __restrict__ rs) {
    const int wid = threadIdx.x >> 6;
    const int lane = threadIdx.x & 63;
    const int row = blockIdx.x * 4 + wid;
    const float4* a = (const float4*)(adj + (size_t)row * NT);
    const float4* b = (const float4*)(adj_s + (size_t)row * NS);
    float sum = 0.f;
#pragma unroll 4
    for (int c = lane; c < NT / 4; c += 64) { float4 v = a[c]; sum += v.x + v.y + v.z + v.w; }
#pragma unroll 4
    for (int c = lane; c < NS / 4; c += 64) { float4 v = b[c]; sum += v.x + v.y + v.z + v.w; }
    for (int off = 32; off > 0; off >>= 1) sum += __shfl_down(sum, off, 64);
    if (lane == 0) rs[row] = sqrtf(sum + 1.0f);
}

// partial column sums, float4 per thread, atomically accumulated into deg[.]
__global__ __launch_bounds__(256)
void colsum_v4_kernel(const float* __restrict__ A, int nrows, int ncols,
                      int rows_per_chunk, float* __restrict__ deg) {
    const int c4 = blockIdx.x * blockDim.x + threadIdx.x;   // float4 column index
    const int r0 = blockIdx.y * rows_per_chunk;
    int r1 = r0 + rows_per_chunk;
    if (r1 > nrows) r1 = nrows;
    const float4* A4 = (const float4*)A;
    const int pitch4 = ncols >> 2;
    float sx = 0.f, sy = 0.f, sz = 0.f, sw = 0.f;
    for (int r = r0; r < r1; ++r) {
        float4 v = A4[(size_t)r * pitch4 + c4];
        sx += v.x; sy += v.y; sz += v.z; sw += v.w;
    }
    float* d = deg + c4 * 4;
    unsafeAtomicAdd(d + 0, sx);
    unsafeAtomicAdd(d + 1, sy);
    unsafeAtomicAdd(d + 2, sz);
    unsafeAtomicAdd(d + 3, sw);
}

__global__ void finish_rt_kernel(float* __restrict__ rt) {
    int t = blockIdx.x * blockDim.x + threadIdx.x;
    if (t < NT) rt[t] = sqrtf(rt[t] + 1.0f);
}

// out[m, :] = (inp[m, :] @ W) / rdeg[m];  inp [M, 256], W [256, 128]  (fp32 VALU)
__global__ __launch_bounds__(256)
void proj_scale_kernel(const float* __restrict__ inp,
                       const float* __restrict__ W,
                       const float* __restrict__ rdeg,
                       float* __restrict__ outp) {
    __shared__ float As[32][68];
    __shared__ float Bs[32][128];
    const int tid = threadIdx.x;
    const int m0 = blockIdx.x * 64;
    const int tx = tid & 15, ty = tid >> 4;
    const int arow = tid >> 3, acg = tid & 7;
    const int bk = tid >> 5, bng = tid & 31;

    float acc[4][8];
#pragma unroll
    for (int r = 0; r < 4; ++r)
#pragma unroll
        for (int c = 0; c < 8; ++c) acc[r][c] = 0.f;

    for (int kt = 0; kt < DIN; kt += 32) {
        const float* Ab = inp + (size_t)(m0 + arow) * DIN + kt + acg * 4;
        float4 a0 = *(const float4*)Ab;
        float4 a1 = *(const float4*)(Ab + (size_t)32 * DIN);
        const float* Bb = W + (size_t)(kt + bk) * DOUT + bng * 4;
        float4 b0 = *(const float4*)Bb;
        float4 b1 = *(const float4*)(Bb + 8 * DOUT);
        float4 b2 = *(const float4*)(Bb + 16 * DOUT);
        float4 b3 = *(const float4*)(Bb + 24 * DOUT);
        __syncthreads();
        As[acg * 4 + 0][arow] = a0.x;
        As[acg * 4 + 1][arow] = a0.y;
        As[acg * 4 + 2][arow] = a0.z;
        As[acg * 4 + 3][arow] = a0.w;
        As[acg * 4 + 0][arow + 32] = a1.x;
        As[acg * 4 + 1][arow + 32] = a1.y;
        As[acg * 4 + 2][arow + 32] = a1.z;
        As[acg * 4 + 3][arow + 32] = a1.w;
        *(float4*)&Bs[bk][bng * 4] = b0;
        *(float4*)&Bs[bk + 8][bng * 4] = b1;
        *(float4*)&Bs[bk + 16][bng * 4] = b2;
        *(float4*)&Bs[bk + 24][bng * 4] = b3;
        __syncthreads();
#pragma unroll
        for (int k = 0; k < 32; ++k) {
            float4 av = *(const float4*)&As[k][ty * 4];
            float4 bv0 = *(const float4*)&Bs[k][tx * 4];
            float4 bv1 = *(const float4*)&Bs[k][tx * 4 + 64];
            float a[4] = {av.x, av.y, av.z, av.w};
            float b[8] = {bv0.x, bv0.y, bv0.z, bv0.w, bv1.x, bv1.y, bv1.z, bv1.w};
#pragma unroll
            for (int r = 0; r < 4; ++r)
#pragma unroll
                for (int c = 0; c < 8; ++c) acc[r][c] = fmaf(a[r], b[c], acc[r][c]);
        }
    }
#pragma unroll
    for (int r = 0; r < 4; ++r) {
        int row = m0 + ty * 4 + r;
        float rd = rdeg[row];
        float* orow = outp + (size_t)row * DOUT;
#pragma unroll
        for (int c = 0; c < 4; ++c) {
            orow[tx * 4 + c] = acc[r][c] / rd;
            orow[tx * 4 + 64 + c] = acc[r][4 + c] / rd;
        }
    }
}

// C[m0:m0+128, 0:128] += op(A)[m0:m0+128, k0:k0+kchunk] @ B[k0:k0+kchunk, 0:128]
// TRANS=0: op(A)=A row-major pitch lda.  TRANS=1: op(A)=A^T, A[k][m] pitch lda.
// BM=128, BN=128, BK=32 (r3 config: LDS 20.5 KB, high occupancy).
// fp32 global -> bf16 LDS -> mfma_f32_16x16x32_bf16, fp32 atomic accumulate into C.
template<int TRANS>
__global__ __launch_bounds__(256)
void gemm_mfma_kernel(const float* __restrict__ A, int lda,
                      const float* __restrict__ B,
                      float* __restrict__ C, int kchunk) {
    __shared__ ushort As[128][40];   // [m][k], pitch 80 B (2-way conflict = free)
    __shared__ ushort Bs[128][40];   // [n][k] (B transposed)
    const int tid = threadIdx.x;
    const int m0 = blockIdx.x * 128;
    const int k0 = blockIdx.y * kchunk;
    const int lane = tid & 63, wid = tid >> 6;
    const int wm = (wid >> 1) * 64, wn = (wid & 1) * 64;
    const int r16 = lane & 15, kg = lane >> 4;

    // staging thread mapping
    const int s_kr = tid >> 3, s_f4 = tid & 7;   // B and TRANS-A: k-row, f4 col group
    const int a_r = tid >> 1, a_seg = tid & 1;   // NN-A: m-row, 16-float segment

    f32x4 acc[4][4];
#pragma unroll
    for (int i = 0; i < 4; ++i)
#pragma unroll
        for (int j = 0; j < 4; ++j) acc[i][j] = (f32x4)(0.f);

    float4 aP[4], bP[4];
    // prefetch kt = 0
    {
        const float* Bb = B + (size_t)(k0 + s_kr) * DOUT + s_f4 * 4;
#pragma unroll
        for (int i = 0; i < 4; ++i) bP[i] = *(const float4*)(Bb + i * 32);
        if (TRANS) {
            const float* Ab = A + (size_t)(k0 + s_kr) * lda + m0 + s_f4 * 4;
#pragma unroll
            for (int i = 0; i < 4; ++i) aP[i] = *(const float4*)(Ab + i * 32);
        } else {
            const float* Ab = A + (size_t)(m0 + a_r) * lda + k0 + a_seg * 16;
#pragma unroll
            for (int i = 0; i < 4; ++i) aP[i] = *(const float4*)(Ab + i * 4);
        }
    }

    for (int kt = 0; kt < kchunk; kt += 32) {
        __syncthreads();   // previous iteration's LDS reads complete
        // convert + store staged tile
        if (TRANS) {
#pragma unroll
            for (int i = 0; i < 4; ++i) {
                int m = s_f4 * 4 + i * 32;
                As[m + 0][s_kr] = f2bf(aP[i].x);
                As[m + 1][s_kr] = f2bf(aP[i].y);
                As[m + 2][s_kr] = f2bf(aP[i].z);
                As[m + 3][s_kr] = f2bf(aP[i].w);
            }
        } else {
            bf8v w0, w1;
            w0[0] = (short)f2bf(aP[0].x); w0[1] = (short)f2bf(aP[0].y);
            w0[2] = (short)f2bf(aP[0].z); w0[3] = (short)f2bf(aP[0].w);
            w0[4] = (short)f2bf(aP[1].x); w0[5] = (short)f2bf(aP[1].y);
            w0[6] = (short)f2bf(aP[1].z); w0[7] = (short)f2bf(aP[1].w);
            w1[0] = (short)f2bf(aP[2].x); w1[1] = (short)f2bf(aP[2].y);
            w1[2] = (short)f2bf(aP[2].z); w1[3] = (short)f2bf(aP[2].w);
            w1[4] = (short)f2bf(aP[3].x); w1[5] = (short)f2bf(aP[3].y);
            w1[6] = (short)f2bf(aP[3].z); w1[7] = (short)f2bf(aP[3].w);
            *(bf8v*)&As[a_r][a_seg * 16] = w0;
            *(bf8v*)&As[a_r][a_seg * 16 + 8] = w1;
        }
#pragma unroll
        for (int i = 0; i < 4; ++i) {
            int n = s_f4 * 4 + i * 32;
            Bs[n + 0][s_kr] = f2bf(bP[i].x);
            Bs[n + 1][s_kr] = f2bf(bP[i].y);
            Bs[n + 2][s_kr] = f2bf(bP[i].z);
            Bs[n + 3][s_kr] = f2bf(bP[i].w);
        }
        __syncthreads();

        // issue next tile's global loads (overlap with MFMA below)
        if (kt + 32 < kchunk) {
            const float* Bb = B + (size_t)(k0 + kt + 32 + s_kr) * DOUT + s_f4 * 4;
#pragma unroll
            for (int i = 0; i < 4; ++i) bP[i] = *(const float4*)(Bb + i * 32);
            if (TRANS) {
                const float* Ab = A + (size_t)(k0 + kt + 32 + s_kr) * lda + m0 + s_f4 * 4;
#pragma unroll
                for (int i = 0; i < 4; ++i) aP[i] = *(const float4*)(Ab + i * 32);
            } else {
                const float* Ab = A + (size_t)(m0 + a_r) * lda + k0 + kt + 32 + a_seg * 16;
#pragma unroll
                for (int i = 0; i < 4; ++i) aP[i] = *(const float4*)(Ab + i * 4);
            }
        }

        // fragments + MFMA
        bf8v af[4], bf[4];
#pragma unroll
        for (int f = 0; f < 4; ++f) af[f] = *(const bf8v*)&As[wm + f * 16 + r16][kg * 8];
#pragma unroll
        for (int f = 0; f < 4; ++f) bf[f] = *(const bf8v*)&Bs[wn + f * 16 + r16][kg * 8];
#pragma unroll
        for (int i = 0; i < 4; ++i)
#pragma unroll
            for (int j = 0; j < 4; ++j)
                acc[i][j] = __builtin_amdgcn_mfma_f32_16x16x32_bf16(af[i], bf[j], acc[i][j], 0, 0, 0);
    }

    // epilogue: atomic accumulate (split-K)
    const int crow0 = m0 + wm + (lane >> 4) * 4;
#pragma unroll
    for (int i = 0; i < 4; ++i) {
#pragma unroll
        for (int j = 0; j < 4; ++j) {
            float* base = C + (size_t)(crow0 + i * 16) * DOUT + wn + j * 16 + r16;
            unsafeAtomicAdd(base + 0 * DOUT, acc[i][j][0]);
            unsafeAtomicAdd(base + 1 * DOUT, acc[i][j][1]);
            unsafeAtomicAdd(base + 2 * DOUT, acc[i][j][2]);
            unsafeAtomicAdd(base + 3 * DOUT, acc[i][j][3]);
        }
    }
}

// x_new = relu(xs + C1/rs) -> d_out;  xns = x_new/rs -> ws
__global__ void epilogue1_kernel(const float* __restrict__ C1,
                                 const float* __restrict__ xs,
                                 const float* __restrict__ rs,
                                 float* __restrict__ outx,
                                 float* __restrict__ xns) {
    int idx = blockIdx.x * blockDim.x + threadIdx.x;
    if (idx >= NS * DOUT) return;
    int row = idx >> 7;
    float r = rs[row];
    float v = xs[idx] + C1[idx] / r;
    v = v > 0.f ? v : 0.f;
    outx[idx] = v;
    xns[idx] = v / r;
}

// y_new = relu(ys + C2/rt) -> d_out + NS*DOUT
__global__ void epilogue2_kernel(const float* __restrict__ C2,
                                 const float* __restrict__ ys,
                                 const float* __restrict__ rt,
                                 float* __restrict__ outy) {
    int idx = blockIdx.x * blockDim.x + threadIdx.x;
    if (idx >= NT * DOUT) return;
    int row = idx >> 7;
    float v = ys[idx] + C2[idx] / rt[row];
    v = v > 0.f ? v : 0.f;
    outy[idx] = v;
}

extern "C" void kernel_launch(void* const* d_in, const int* in_sizes, int n_in,
                              void* d_out, int out_size, void* d_ws, size_t ws_size,
                              hipStream_t stream) {
    const float* inp_s = (const float*)d_in[0];
    const float* inp_t = (const float*)d_in[1];
    const float* adj   = (const float*)d_in[2];
    const float* adj_s = (const float*)d_in[3];
    const float* adj_t = (const float*)d_in[4];
    const float* W     = (const float*)d_in[5];
    float* out = (float*)d_out;
    float* ws  = (float*)d_ws;

    float* rs  = ws + OFF_RS;
    float* rt  = ws + OFF_RT;   // deg_to, then rt in place
    float* C1  = ws + OFF_C1;
    float* C2  = ws + OFF_C2;
    float* xs  = ws + OFF_XS;
    float* ys  = ws + OFF_YS;
    float* xns = ws + OFF_XNS;

    // zero deg_to + C1 + C2 (contiguous region [OFF_RT, OFF_XS))
    int nz4 = (OFF_XS - OFF_RT) / 4;
    zero_kernel<<<1024, 256, 0, stream>>>(rt, nz4);

    // degrees (fp32, streaming)
    rowsum_rs_kernel<<<NS / 4, 256, 0, stream>>>(adj, adj_s, rs);
    colsum_v4_kernel<<<dim3(NT / 1024, 128), 256, 0, stream>>>(adj, NS, NT, 32, rt);
    colsum_v4_kernel<<<dim3(NT / 1024, 128), 256, 0, stream>>>(adj_t, NT, NT, 64, rt);
    finish_rt_kernel<<<NT / 256, 256, 0, stream>>>(rt);

    // projections, pre-scaled: xs = (inp_s@W)/rs, ys = (inp_t@W)/rt
    proj_scale_kernel<<<NS / 64, 256, 0, stream>>>(inp_s, W, rs, xs);
    proj_scale_kernel<<<NT / 64, 256, 0, stream>>>(inp_t, W, rt, ys);

    // C1 = adj_s@xs + adj@ys   [NS,128]   (bf16 MFMA, split-K 16 for grid occupancy)
    gemm_mfma_kernel<0><<<dim3(NS / 128, 16), 256, 0, stream>>>(adj_s, NS, xs, C1, NS / 16);
    gemm_mfma_kernel<0><<<dim3(NS / 128, 16), 256, 0, stream>>>(adj, NT, ys, C1, NT / 16);
    epilogue1_kernel<<<(NS * DOUT) / 256, 256, 0, stream>>>(C1, xs, rs, out, xns);

    // C2 = adj_t@ys + adj^T@xns   [NT,128]
    gemm_mfma_kernel<0><<<dim3(NT / 128, 16), 256, 0, stream>>>(adj_t, NT, ys, C2, NT / 16);
    gemm_mfma_kernel<1><<<dim3(NT / 128, 16), 256, 0, stream>>>(adj, NT, xns, C2, NS / 16);
    epilogue2_kernel<<<(NT * DOUT) / 256, 256, 0, stream>>>(C2, ys, rt, out + NS * DOUT);
}

// Round 8
// 393.453 us; speedup vs baseline: 1.1834x; 1.1646x over previous
//
#include <hip/hip_runtime.h>

#define NS 4096
#define NT 8192
#define DIN 256
#define DOUT 128

// float offsets into workspace
#define OFF_RS   0                       // deg_s then rs in place [NS]
#define OFF_RT   (NS)                    // deg_t then rt in place [NT]
#define OFF_C1   (OFF_RT + NT)           // 12288
#define OFF_C2   (OFF_C1 + NS*DOUT)      // 536576
#define OFF_XS   (OFF_C2 + NT*DOUT)      // 1585152
#define OFF_YS   (OFF_XS + NS*DOUT)
#define OFF_XNS  (OFF_YS + NT*DOUT)

typedef __attribute__((ext_vector_type(8))) short bf8v;
typedef __attribute__((ext_vector_type(4))) float f32x4;

__device__ __forceinline__ ushort f2bf(float f) {
    // exact round-to-nearest-even fp32 -> bf16 (finite inputs only)
    unsigned x = __float_as_uint(f);
    unsigned r = (x + 0x7fffu + ((x >> 16) & 1u)) >> 16;
    return (ushort)r;
}

__global__ void zero_kernel(float* __restrict__ p, int n4) {
    int i = blockIdx.x * blockDim.x + threadIdx.x;
    int stride = gridDim.x * blockDim.x;
    float4* p4 = (float4*)p;
    float4 z = make_float4(0.f, 0.f, 0.f, 0.f);
    for (; i < n4; i += stride) p4[i] = z;
}

// One pass over adj: row partials -> deg_s (atomic), col partials -> deg_t (atomic)
__global__ __launch_bounds__(256)
void adj_deg_kernel(const float* __restrict__ adj,
                    float* __restrict__ deg_s, float* __restrict__ deg_t) {
    const int tid = threadIdx.x;
    const int lane = tid & 63;
    const int c4 = blockIdx.x * 256 + tid;          // float4 column
    const int r0 = blockIdx.y * 32;
    const float4* A4 = (const float4*)adj + (size_t)r0 * (NT / 4) + c4;
    float sx = 0.f, sy = 0.f, sz = 0.f, sw = 0.f;
#pragma unroll 8
    for (int r = 0; r < 32; ++r) {
        float4 v = A4[(size_t)r * (NT / 4)];
        sx += v.x; sy += v.y; sz += v.z; sw += v.w;
        float rp = v.x + v.y + v.z + v.w;
#pragma unroll
        for (int off = 32; off > 0; off >>= 1) rp += __shfl_down(rp, off, 64);
        if (lane == 0) unsafeAtomicAdd(deg_s + r0 + r, rp);
    }
    float* d = deg_t + c4 * 4;
    unsafeAtomicAdd(d + 0, sx);
    unsafeAtomicAdd(d + 1, sy);
    unsafeAtomicAdd(d + 2, sz);
    unsafeAtomicAdd(d + 3, sw);
}

// adj_s row sums -> deg_s (atomic); one wave per row
__global__ __launch_bounds__(256)
void rowsum_s_kernel(const float* __restrict__ adj_s, float* __restrict__ deg_s) {
    const int wid = threadIdx.x >> 6;
    const int lane = threadIdx.x & 63;
    const int row = blockIdx.x * 4 + wid;
    const float4* b = (const float4*)(adj_s + (size_t)row * NS);
    float sum = 0.f;
#pragma unroll 8
    for (int c = lane; c < NS / 4; c += 64) { float4 v = b[c]; sum += v.x + v.y + v.z + v.w; }
#pragma unroll
    for (int off = 32; off > 0; off >>= 1) sum += __shfl_down(sum, off, 64);
    if (lane == 0) unsafeAtomicAdd(deg_s + row, sum);
}

// adj_t col partial sums -> deg_t (atomic); float4 per thread
__global__ __launch_bounds__(256)
void colsum_t_kernel(const float* __restrict__ A, float* __restrict__ deg_t) {
    const int c4 = blockIdx.x * 256 + threadIdx.x;
    const int r0 = blockIdx.y * 64;
    const float4* A4 = (const float4*)A + (size_t)r0 * (NT / 4) + c4;
    float sx = 0.f, sy = 0.f, sz = 0.f, sw = 0.f;
#pragma unroll 8
    for (int r = 0; r < 64; ++r) {
        float4 v = A4[(size_t)r * (NT / 4)];
        sx += v.x; sy += v.y; sz += v.z; sw += v.w;
    }
    float* d = deg_t + c4 * 4;
    unsafeAtomicAdd(d + 0, sx);
    unsafeAtomicAdd(d + 1, sy);
    unsafeAtomicAdd(d + 2, sz);
    unsafeAtomicAdd(d + 3, sw);
}

// deg -> sqrt(deg + 1), in place over rs|rt (contiguous NS+NT)
__global__ void finish_deg_kernel(float* __restrict__ deg) {
    int t = blockIdx.x * blockDim.x + threadIdx.x;
    deg[t] = sqrtf(deg[t] + 1.0f);
}

// out[m, :] = (inp[m, :] @ W) / rdeg[m];  inp [M, 256], W [256, 128]  (fp32 VALU)
__global__ __launch_bounds__(256)
void proj_scale_kernel(const float* __restrict__ inp,
                       const float* __restrict__ W,
                       const float* __restrict__ rdeg,
                       float* __restrict__ outp) {
    __shared__ float As[32][68];
    __shared__ float Bs[32][128];
    const int tid = threadIdx.x;
    const int m0 = blockIdx.x * 64;
    const int tx = tid & 15, ty = tid >> 4;
    const int arow = tid >> 3, acg = tid & 7;
    const int bk = tid >> 5, bng = tid & 31;

    float acc[4][8];
#pragma unroll
    for (int r = 0; r < 4; ++r)
#pragma unroll
        for (int c = 0; c < 8; ++c) acc[r][c] = 0.f;

    for (int kt = 0; kt < DIN; kt += 32) {
        const float* Ab = inp + (size_t)(m0 + arow) * DIN + kt + acg * 4;
        float4 a0 = *(const float4*)Ab;
        float4 a1 = *(const float4*)(Ab + (size_t)32 * DIN);
        const float* Bb = W + (size_t)(kt + bk) * DOUT + bng * 4;
        float4 b0 = *(const float4*)Bb;
        float4 b1 = *(const float4*)(Bb + 8 * DOUT);
        float4 b2 = *(const float4*)(Bb + 16 * DOUT);
        float4 b3 = *(const float4*)(Bb + 24 * DOUT);
        __syncthreads();
        As[acg * 4 + 0][arow] = a0.x;
        As[acg * 4 + 1][arow] = a0.y;
        As[acg * 4 + 2][arow] = a0.z;
        As[acg * 4 + 3][arow] = a0.w;
        As[acg * 4 + 0][arow + 32] = a1.x;
        As[acg * 4 + 1][arow + 32] = a1.y;
        As[acg * 4 + 2][arow + 32] = a1.z;
        As[acg * 4 + 3][arow + 32] = a1.w;
        *(float4*)&Bs[bk][bng * 4] = b0;
        *(float4*)&Bs[bk + 8][bng * 4] = b1;
        *(float4*)&Bs[bk + 16][bng * 4] = b2;
        *(float4*)&Bs[bk + 24][bng * 4] = b3;
        __syncthreads();
#pragma unroll
        for (int k = 0; k < 32; ++k) {
            float4 av = *(const float4*)&As[k][ty * 4];
            float4 bv0 = *(const float4*)&Bs[k][tx * 4];
            float4 bv1 = *(const float4*)&Bs[k][tx * 4 + 64];
            float a[4] = {av.x, av.y, av.z, av.w};
            float b[8] = {bv0.x, bv0.y, bv0.z, bv0.w, bv1.x, bv1.y, bv1.z, bv1.w};
#pragma unroll
            for (int r = 0; r < 4; ++r)
#pragma unroll
                for (int c = 0; c < 8; ++c) acc[r][c] = fmaf(a[r], b[c], acc[r][c]);
        }
    }
#pragma unroll
    for (int r = 0; r < 4; ++r) {
        int row = m0 + ty * 4 + r;
        float rd = rdeg[row];
        float* orow = outp + (size_t)row * DOUT;
#pragma unroll
        for (int c = 0; c < 4; ++c) {
            orow[tx * 4 + c] = acc[r][c] / rd;
            orow[tx * 4 + 64 + c] = acc[r][4 + c] / rd;
        }
    }
}

// C[m0:m0+128, 0:128] += op(A)[m0:m0+128, k0:k0+kchunk] @ B[k0:k0+kchunk, 0:128]
// TRANS=0: op(A)=A row-major pitch lda.  TRANS=1: op(A)=A^T, A[k][m] pitch lda.
// BM=128, BN=128, BK=32 (r3 config: LDS 20.5 KB).
template<int TRANS>
__global__ __launch_bounds__(256)
void gemm_mfma_kernel(const float* __restrict__ A, int lda,
                      const float* __restrict__ B,
                      float* __restrict__ C, int kchunk) {
    __shared__ ushort As[128][40];   // [m][k], pitch 80 B (2-way conflict = free)
    __shared__ ushort Bs[128][40];   // [n][k] (B transposed)
    const int tid = threadIdx.x;
    const int m0 = blockIdx.x * 128;
    const int k0 = blockIdx.y * kchunk;
    const int lane = tid & 63, wid = tid >> 6;
    const int wm = (wid >> 1) * 64, wn = (wid & 1) * 64;
    const int r16 = lane & 15, kg = lane >> 4;

    const int s_kr = tid >> 3, s_f4 = tid & 7;   // B and TRANS-A: k-row, f4 col group
    const int a_r = tid >> 1, a_seg = tid & 1;   // NN-A: m-row, 16-float segment

    f32x4 acc[4][4];
#pragma unroll
    for (int i = 0; i < 4; ++i)
#pragma unroll
        for (int j = 0; j < 4; ++j) acc[i][j] = (f32x4)(0.f);

    float4 aP[4], bP[4];
    {
        const float* Bb = B + (size_t)(k0 + s_kr) * DOUT + s_f4 * 4;
#pragma unroll
        for (int i = 0; i < 4; ++i) bP[i] = *(const float4*)(Bb + i * 32);
        if (TRANS) {
            const float* Ab = A + (size_t)(k0 + s_kr) * lda + m0 + s_f4 * 4;
#pragma unroll
            for (int i = 0; i < 4; ++i) aP[i] = *(const float4*)(Ab + i * 32);
        } else {
            const float* Ab = A + (size_t)(m0 + a_r) * lda + k0 + a_seg * 16;
#pragma unroll
            for (int i = 0; i < 4; ++i) aP[i] = *(const float4*)(Ab + i * 4);
        }
    }

    for (int kt = 0; kt < kchunk; kt += 32) {
        __syncthreads();
        if (TRANS) {
#pragma unroll
            for (int i = 0; i < 4; ++i) {
                int m = s_f4 * 4 + i * 32;
                As[m + 0][s_kr] = f2bf(aP[i].x);
                As[m + 1][s_kr] = f2bf(aP[i].y);
                As[m + 2][s_kr] = f2bf(aP[i].z);
                As[m + 3][s_kr] = f2bf(aP[i].w);
            }
        } else {
            bf8v w0, w1;
            w0[0] = (short)f2bf(aP[0].x); w0[1] = (short)f2bf(aP[0].y);
            w0[2] = (short)f2bf(aP[0].z); w0[3] = (short)f2bf(aP[0].w);
            w0[4] = (short)f2bf(aP[1].x); w0[5] = (short)f2bf(aP[1].y);
            w0[6] = (short)f2bf(aP[1].z); w0[7] = (short)f2bf(aP[1].w);
            w1[0] = (short)f2bf(aP[2].x); w1[1] = (short)f2bf(aP[2].y);
            w1[2] = (short)f2bf(aP[2].z); w1[3] = (short)f2bf(aP[2].w);
            w1[4] = (short)f2bf(aP[3].x); w1[5] = (short)f2bf(aP[3].y);
            w1[6] = (short)f2bf(aP[3].z); w1[7] = (short)f2bf(aP[3].w);
            *(bf8v*)&As[a_r][a_seg * 16] = w0;
            *(bf8v*)&As[a_r][a_seg * 16 + 8] = w1;
        }
#pragma unroll
        for (int i = 0; i < 4; ++i) {
            int n = s_f4 * 4 + i * 32;
            Bs[n + 0][s_kr] = f2bf(bP[i].x);
            Bs[n + 1][s_kr] = f2bf(bP[i].y);
            Bs[n + 2][s_kr] = f2bf(bP[i].z);
            Bs[n + 3][s_kr] = f2bf(bP[i].w);
        }
        __syncthreads();

        if (kt + 32 < kchunk) {
            const float* Bb = B + (size_t)(k0 + kt + 32 + s_kr) * DOUT + s_f4 * 4;
#pragma unroll
            for (int i = 0; i < 4; ++i) bP[i] = *(const float4*)(Bb + i * 32);
            if (TRANS) {
                const float* Ab = A + (size_t)(k0 + kt + 32 + s_kr) * lda + m0 + s_f4 * 4;
#pragma unroll
                for (int i = 0; i < 4; ++i) aP[i] = *(const float4*)(Ab + i * 32);
            } else {
                const float* Ab = A + (size_t)(m0 + a_r) * lda + k0 + kt + 32 + a_seg * 16;
#pragma unroll
                for (int i = 0; i < 4; ++i) aP[i] = *(const float4*)(Ab + i * 4);
            }
        }

        bf8v af[4], bf[4];
#pragma unroll
        for (int f = 0; f < 4; ++f) af[f] = *(const bf8v*)&As[wm + f * 16 + r16][kg * 8];
#pragma unroll
        for (int f = 0; f < 4; ++f) bf[f] = *(const bf8v*)&Bs[wn + f * 16 + r16][kg * 8];
#pragma unroll
        for (int i = 0; i < 4; ++i)
#pragma unroll
            for (int j = 0; j < 4; ++j)
                acc[i][j] = __builtin_amdgcn_mfma_f32_16x16x32_bf16(af[i], bf[j], acc[i][j], 0, 0, 0);
    }

    const int crow0 = m0 + wm + (lane >> 4) * 4;
#pragma unroll
    for (int i = 0; i < 4; ++i) {
#pragma unroll
        for (int j = 0; j < 4; ++j) {
            float* base = C + (size_t)(crow0 + i * 16) * DOUT + wn + j * 16 + r16;
            unsafeAtomicAdd(base + 0 * DOUT, acc[i][j][0]);
            unsafeAtomicAdd(base + 1 * DOUT, acc[i][j][1]);
            unsafeAtomicAdd(base + 2 * DOUT, acc[i][j][2]);
            unsafeAtomicAdd(base + 3 * DOUT, acc[i][j][3]);
        }
    }
}

// x_new = relu(xs + C1/rs) -> d_out;  xns = x_new/rs -> ws
__global__ void epilogue1_kernel(const float* __restrict__ C1,
                                 const float* __restrict__ xs,
                                 const float* __restrict__ rs,
                                 float* __restrict__ outx,
                                 float* __restrict__ xns) {
    int idx = blockIdx.x * blockDim.x + threadIdx.x;
    if (idx >= NS * DOUT) return;
    int row = idx >> 7;
    float r = rs[row];
    float v = xs[idx] + C1[idx] / r;
    v = v > 0.f ? v : 0.f;
    outx[idx] = v;
    xns[idx] = v / r;
}

// y_new = relu(ys + C2/rt) -> d_out + NS*DOUT
__global__ void epilogue2_kernel(const float* __restrict__ C2,
                                 const float* __restrict__ ys,
                                 const float* __restrict__ rt,
                                 float* __restrict__ outy) {
    int idx = blockIdx.x * blockDim.x + threadIdx.x;
    if (idx >= NT * DOUT) return;
    int row = idx >> 7;
    float v = ys[idx] + C2[idx] / rt[row];
    v = v > 0.f ? v : 0.f;
    outy[idx] = v;
}

extern "C" void kernel_launch(void* const* d_in, const int* in_sizes, int n_in,
                              void* d_out, int out_size, void* d_ws, size_t ws_size,
                              hipStream_t stream) {
    const float* inp_s = (const float*)d_in[0];
    const float* inp_t = (const float*)d_in[1];
    const float* adj   = (const float*)d_in[2];
    const float* adj_s = (const float*)d_in[3];
    const float* adj_t = (const float*)d_in[4];
    const float* W     = (const float*)d_in[5];
    float* out = (float*)d_out;
    float* ws  = (float*)d_ws;

    float* rs  = ws + OFF_RS;
    float* rt  = ws + OFF_RT;
    float* C1  = ws + OFF_C1;
    float* C2  = ws + OFF_C2;
    float* xs  = ws + OFF_XS;
    float* ys  = ws + OFF_YS;
    float* xns = ws + OFF_XNS;

    // zero deg_s + deg_t + C1 + C2 (contiguous [0, OFF_XS))
    zero_kernel<<<1024, 256, 0, stream>>>(ws, OFF_XS / 4);

    // Degree pass, ordered for LLC residency in the GEMM phase:
    // stream adj_t (268 MB) FIRST so adj (134 MB) + adj_s (67 MB) are the
    // last reads and stay resident in the 256 MB Infinity Cache.
    colsum_t_kernel<<<dim3(NT / 1024, NT / 64), 256, 0, stream>>>(adj_t, rt);
    adj_deg_kernel<<<dim3(NT / 1024, NS / 32), 256, 0, stream>>>(adj, rs, rt);
    rowsum_s_kernel<<<NS / 4, 256, 0, stream>>>(adj_s, rs);
    finish_deg_kernel<<<(NS + NT) / 256, 256, 0, stream>>>(rs);   // rs|rt contiguous

    // projections, pre-scaled: xs = (inp_s@W)/rs, ys = (inp_t@W)/rt
    proj_scale_kernel<<<NS / 64, 256, 0, stream>>>(inp_s, W, rs, xs);
    proj_scale_kernel<<<NT / 64, 256, 0, stream>>>(inp_t, W, rt, ys);

    // GEMMs ordered LLC-warm first, adj_t (cold, 268 MB) last.
    // C1 = adj_s@xs + adj@ys   [NS,128]
    gemm_mfma_kernel<0><<<dim3(NS / 128, 8), 256, 0, stream>>>(adj_s, NS, xs, C1, NS / 8);
    gemm_mfma_kernel<0><<<dim3(NS / 128, 8), 256, 0, stream>>>(adj, NT, ys, C1, NT / 8);
    epilogue1_kernel<<<(NS * DOUT) / 256, 256, 0, stream>>>(C1, xs, rs, out, xns);

    // C2 = adj^T@xns + adj_t@ys   [NT,128]
    gemm_mfma_kernel<1><<<dim3(NT / 128, 8), 256, 0, stream>>>(adj, NT, xns, C2, NS / 8);
    gemm_mfma_kernel<0><<<dim3(NT / 128, 8), 256, 0, stream>>>(adj_t, NT, ys, C2, NT / 8);
    epilogue2_kernel<<<(NT * DOUT) / 256, 256, 0, stream>>>(C2, ys, rt, out + NS * DOUT);
}

// Round 9
// 380.991 us; speedup vs baseline: 1.2221x; 1.0327x over previous
//
#include <hip/hip_runtime.h>

#define NS 4096
#define NT 8192
#define DIN 256
#define DOUT 128

// float offsets into workspace
#define OFF_RS   0                       // deg_s then rs in place [NS]
#define OFF_RT   (NS)                    // deg_t then rt in place [NT]
#define OFF_C1   (OFF_RT + NT)           // 12288
#define OFF_C2   (OFF_C1 + NS*DOUT)
#define OFF_XS   (OFF_C2 + NT*DOUT)
#define OFF_YS   (OFF_XS + NS*DOUT)
#define OFF_XNS  (OFF_YS + NT*DOUT)
#define OFF_XST  (OFF_XNS + NS*DOUT)               // bf16 [128][NS] = 262144 floats
#define OFF_YST  (OFF_XST + (128*NS)/2)            // bf16 [128][NT] = 524288 floats

typedef __attribute__((ext_vector_type(8))) short bf8v;
typedef __attribute__((ext_vector_type(4))) float f32x4;
typedef __attribute__((ext_vector_type(4))) unsigned short u16x4;

__device__ __forceinline__ ushort f2bf(float f) {
    // exact round-to-nearest-even fp32 -> bf16 (finite inputs only)
    unsigned x = __float_as_uint(f);
    unsigned r = (x + 0x7fffu + ((x >> 16) & 1u)) >> 16;
    return (ushort)r;
}

__global__ void zero_kernel(float* __restrict__ p, int n4) {
    int i = blockIdx.x * blockDim.x + threadIdx.x;
    int stride = gridDim.x * blockDim.x;
    float4* p4 = (float4*)p;
    float4 z = make_float4(0.f, 0.f, 0.f, 0.f);
    for (; i < n4; i += stride) p4[i] = z;
}

// One pass over adj: row partials -> deg_s (atomic), col partials -> deg_t (atomic)
__global__ __launch_bounds__(256)
void adj_deg_kernel(const float* __restrict__ adj,
                    float* __restrict__ deg_s, float* __restrict__ deg_t) {
    const int tid = threadIdx.x;
    const int lane = tid & 63;
    const int c4 = blockIdx.x * 256 + tid;          // float4 column
    const int r0 = blockIdx.y * 32;
    const float4* A4 = (const float4*)adj + (size_t)r0 * (NT / 4) + c4;
    float sx = 0.f, sy = 0.f, sz = 0.f, sw = 0.f;
#pragma unroll 8
    for (int r = 0; r < 32; ++r) {
        float4 v = A4[(size_t)r * (NT / 4)];
        sx += v.x; sy += v.y; sz += v.z; sw += v.w;
        float rp = v.x + v.y + v.z + v.w;
#pragma unroll
        for (int off = 32; off > 0; off >>= 1) rp += __shfl_down(rp, off, 64);
        if (lane == 0) unsafeAtomicAdd(deg_s + r0 + r, rp);
    }
    float* d = deg_t + c4 * 4;
    unsafeAtomicAdd(d + 0, sx);
    unsafeAtomicAdd(d + 1, sy);
    unsafeAtomicAdd(d + 2, sz);
    unsafeAtomicAdd(d + 3, sw);
}

// adj_s row sums -> deg_s (atomic); one wave per row
__global__ __launch_bounds__(256)
void rowsum_s_kernel(const float* __restrict__ adj_s, float* __restrict__ deg_s) {
    const int wid = threadIdx.x >> 6;
    const int lane = threadIdx.x & 63;
    const int row = blockIdx.x * 4 + wid;
    const float4* b = (const float4*)(adj_s + (size_t)row * NS);
    float sum = 0.f;
#pragma unroll 8
    for (int c = lane; c < NS / 4; c += 64) { float4 v = b[c]; sum += v.x + v.y + v.z + v.w; }
#pragma unroll
    for (int off = 32; off > 0; off >>= 1) sum += __shfl_down(sum, off, 64);
    if (lane == 0) unsafeAtomicAdd(deg_s + row, sum);
}

// adj_t col partial sums -> deg_t (atomic); float4 per thread
__global__ __launch_bounds__(256)
void colsum_t_kernel(const float* __restrict__ A, float* __restrict__ deg_t) {
    const int c4 = blockIdx.x * 256 + threadIdx.x;
    const int r0 = blockIdx.y * 64;
    const float4* A4 = (const float4*)A + (size_t)r0 * (NT / 4) + c4;
    float sx = 0.f, sy = 0.f, sz = 0.f, sw = 0.f;
#pragma unroll 8
    for (int r = 0; r < 64; ++r) {
        float4 v = A4[(size_t)r * (NT / 4)];
        sx += v.x; sy += v.y; sz += v.z; sw += v.w;
    }
    float* d = deg_t + c4 * 4;
    unsafeAtomicAdd(d + 0, sx);
    unsafeAtomicAdd(d + 1, sy);
    unsafeAtomicAdd(d + 2, sz);
    unsafeAtomicAdd(d + 3, sw);
}

// deg -> sqrt(deg + 1), in place over rs|rt (contiguous NS+NT)
__global__ void finish_deg_kernel(float* __restrict__ deg) {
    int t = blockIdx.x * blockDim.x + threadIdx.x;
    deg[t] = sqrtf(deg[t] + 1.0f);
}

// out[m,:] = (inp[m,:] @ W) / rdeg[m]  (fp32), plus outT[n][m] = bf16(out[m][n])
__global__ __launch_bounds__(256)
void proj_scale_kernel(const float* __restrict__ inp,
                       const float* __restrict__ W,
                       const float* __restrict__ rdeg,
                       float* __restrict__ outp,
                       ushort* __restrict__ outT, int M) {
    __shared__ float As[32][68];
    __shared__ float Bs[32][128];
    const int tid = threadIdx.x;
    const int m0 = blockIdx.x * 64;
    const int tx = tid & 15, ty = tid >> 4;
    const int arow = tid >> 3, acg = tid & 7;
    const int bk = tid >> 5, bng = tid & 31;

    float acc[4][8];
#pragma unroll
    for (int r = 0; r < 4; ++r)
#pragma unroll
        for (int c = 0; c < 8; ++c) acc[r][c] = 0.f;

    for (int kt = 0; kt < DIN; kt += 32) {
        const float* Ab = inp + (size_t)(m0 + arow) * DIN + kt + acg * 4;
        float4 a0 = *(const float4*)Ab;
        float4 a1 = *(const float4*)(Ab + (size_t)32 * DIN);
        const float* Bb = W + (size_t)(kt + bk) * DOUT + bng * 4;
        float4 b0 = *(const float4*)Bb;
        float4 b1 = *(const float4*)(Bb + 8 * DOUT);
        float4 b2 = *(const float4*)(Bb + 16 * DOUT);
        float4 b3 = *(const float4*)(Bb + 24 * DOUT);
        __syncthreads();
        As[acg * 4 + 0][arow] = a0.x;
        As[acg * 4 + 1][arow] = a0.y;
        As[acg * 4 + 2][arow] = a0.z;
        As[acg * 4 + 3][arow] = a0.w;
        As[acg * 4 + 0][arow + 32] = a1.x;
        As[acg * 4 + 1][arow + 32] = a1.y;
        As[acg * 4 + 2][arow + 32] = a1.z;
        As[acg * 4 + 3][arow + 32] = a1.w;
        *(float4*)&Bs[bk][bng * 4] = b0;
        *(float4*)&Bs[bk + 8][bng * 4] = b1;
        *(float4*)&Bs[bk + 16][bng * 4] = b2;
        *(float4*)&Bs[bk + 24][bng * 4] = b3;
        __syncthreads();
#pragma unroll
        for (int k = 0; k < 32; ++k) {
            float4 av = *(const float4*)&As[k][ty * 4];
            float4 bv0 = *(const float4*)&Bs[k][tx * 4];
            float4 bv1 = *(const float4*)&Bs[k][tx * 4 + 64];
            float a[4] = {av.x, av.y, av.z, av.w};
            float b[8] = {bv0.x, bv0.y, bv0.z, bv0.w, bv1.x, bv1.y, bv1.z, bv1.w};
#pragma unroll
            for (int r = 0; r < 4; ++r)
#pragma unroll
                for (int c = 0; c < 8; ++c) acc[r][c] = fmaf(a[r], b[c], acc[r][c]);
        }
    }
    float rds[4];
#pragma unroll
    for (int r = 0; r < 4; ++r) rds[r] = rdeg[m0 + ty * 4 + r];
    // scale in place, write fp32 row-major
#pragma unroll
    for (int r = 0; r < 4; ++r) {
        int row = m0 + ty * 4 + r;
        float* orow = outp + (size_t)row * DOUT;
#pragma unroll
        for (int c = 0; c < 8; ++c) acc[r][c] /= rds[r];
#pragma unroll
        for (int c = 0; c < 4; ++c) {
            orow[tx * 4 + c] = acc[r][c];
            orow[tx * 4 + 64 + c] = acc[r][4 + c];
        }
    }
    // write bf16 transposed: outT[col][m0+ty*4 .. +3]
#pragma unroll
    for (int c = 0; c < 8; ++c) {
        int col = tx * 4 + (c & 3) + (c >> 2) * 64;
        u16x4 w;
#pragma unroll
        for (int r = 0; r < 4; ++r) w[r] = f2bf(acc[r][c]);
        *(u16x4*)&outT[(size_t)col * M + m0 + ty * 4] = w;
    }
}

// C[m0:m0+128, 0:128] += op(A)[m0:m0+128, k0:k0+kchunk] @ B[k0:k0+kchunk, 0:128]
// TRANS=0: op(A)=A row-major pitch lda.  TRANS=1: op(A)=A^T, A[k][m] pitch lda.
// BTF=1: B supplied as bf16 transposed bT[n][k] pitch ldb (no convert/scatter).
// BTF=0: B supplied as fp32 row-major Bf[k][n] pitch DOUT (legacy path).
template<int TRANS, int BTF>
__global__ __launch_bounds__(256)
void gemm_mfma_kernel(const float* __restrict__ A, int lda,
                      const float* __restrict__ Bf,
                      const ushort* __restrict__ bT, int ldb,
                      float* __restrict__ C, int kchunk) {
    __shared__ ushort As[128][40];   // [m][k], pitch 80 B
    __shared__ ushort Bs[128][40];   // [n][k]
    const int tid = threadIdx.x;
    const int m0 = blockIdx.x * 128;
    const int k0 = blockIdx.y * kchunk;
    const int lane = tid & 63, wid = tid >> 6;
    const int wm = (wid >> 1) * 64, wn = (wid & 1) * 64;
    const int r16 = lane & 15, kg = lane >> 4;

    const int s_kr = tid >> 3, s_f4 = tid & 7;   // fp32-B / TRANS-A staging map
    const int a_r = tid >> 1, a_seg = tid & 1;   // NN-A staging map
    const int t_n = tid >> 2, t_seg = tid & 3;   // bf16-T B staging map

    f32x4 acc[4][4];
#pragma unroll
    for (int i = 0; i < 4; ++i)
#pragma unroll
        for (int j = 0; j < 4; ++j) acc[i][j] = (f32x4)(0.f);

    float4 aP[4], bP[4];
    bf8v bPT[2];

    auto loadB = [&](int ktb) {
        if (BTF) {
#pragma unroll
            for (int p = 0; p < 2; ++p)
                bPT[p] = *(const bf8v*)(bT + (size_t)(t_n + p * 64) * ldb + k0 + ktb + t_seg * 8);
        } else {
            const float* Bb = Bf + (size_t)(k0 + ktb + s_kr) * DOUT + s_f4 * 4;
#pragma unroll
            for (int i = 0; i < 4; ++i) bP[i] = *(const float4*)(Bb + i * 32);
        }
    };
    auto loadA = [&](int ktb) {
        if (TRANS) {
            const float* Ab = A + (size_t)(k0 + ktb + s_kr) * lda + m0 + s_f4 * 4;
#pragma unroll
            for (int i = 0; i < 4; ++i) aP[i] = *(const float4*)(Ab + i * 32);
        } else {
            const float* Ab = A + (size_t)(m0 + a_r) * lda + k0 + ktb + a_seg * 16;
#pragma unroll
            for (int i = 0; i < 4; ++i) aP[i] = *(const float4*)(Ab + i * 4);
        }
    };

    loadB(0); loadA(0);

    for (int kt = 0; kt < kchunk; kt += 32) {
        __syncthreads();
        // store staged tiles
        if (TRANS) {
#pragma unroll
            for (int i = 0; i < 4; ++i) {
                int m = s_f4 * 4 + i * 32;
                As[m + 0][s_kr] = f2bf(aP[i].x);
                As[m + 1][s_kr] = f2bf(aP[i].y);
                As[m + 2][s_kr] = f2bf(aP[i].z);
                As[m + 3][s_kr] = f2bf(aP[i].w);
            }
        } else {
            bf8v w0, w1;
            w0[0] = (short)f2bf(aP[0].x); w0[1] = (short)f2bf(aP[0].y);
            w0[2] = (short)f2bf(aP[0].z); w0[3] = (short)f2bf(aP[0].w);
            w0[4] = (short)f2bf(aP[1].x); w0[5] = (short)f2bf(aP[1].y);
            w0[6] = (short)f2bf(aP[1].z); w0[7] = (short)f2bf(aP[1].w);
            w1[0] = (short)f2bf(aP[2].x); w1[1] = (short)f2bf(aP[2].y);
            w1[2] = (short)f2bf(aP[2].z); w1[3] = (short)f2bf(aP[2].w);
            w1[4] = (short)f2bf(aP[3].x); w1[5] = (short)f2bf(aP[3].y);
            w1[6] = (short)f2bf(aP[3].z); w1[7] = (short)f2bf(aP[3].w);
            *(bf8v*)&As[a_r][a_seg * 16] = w0;
            *(bf8v*)&As[a_r][a_seg * 16 + 8] = w1;
        }
        if (BTF) {
#pragma unroll
            for (int p = 0; p < 2; ++p)
                *(bf8v*)&Bs[t_n + p * 64][t_seg * 8] = bPT[p];
        } else {
#pragma unroll
            for (int i = 0; i < 4; ++i) {
                int n = s_f4 * 4 + i * 32;
                Bs[n + 0][s_kr] = f2bf(bP[i].x);
                Bs[n + 1][s_kr] = f2bf(bP[i].y);
                Bs[n + 2][s_kr] = f2bf(bP[i].z);
                Bs[n + 3][s_kr] = f2bf(bP[i].w);
            }
        }
        __syncthreads();

        if (kt + 32 < kchunk) { loadB(kt + 32); loadA(kt + 32); }

        bf8v af[4], bf[4];
#pragma unroll
        for (int f = 0; f < 4; ++f) af[f] = *(const bf8v*)&As[wm + f * 16 + r16][kg * 8];
#pragma unroll
        for (int f = 0; f < 4; ++f) bf[f] = *(const bf8v*)&Bs[wn + f * 16 + r16][kg * 8];
#pragma unroll
        for (int i = 0; i < 4; ++i)
#pragma unroll
            for (int j = 0; j < 4; ++j)
                acc[i][j] = __builtin_amdgcn_mfma_f32_16x16x32_bf16(af[i], bf[j], acc[i][j], 0, 0, 0);
    }

    const int crow0 = m0 + wm + (lane >> 4) * 4;
#pragma unroll
    for (int i = 0; i < 4; ++i) {
#pragma unroll
        for (int j = 0; j < 4; ++j) {
            float* base = C + (size_t)(crow0 + i * 16) * DOUT + wn + j * 16 + r16;
            unsafeAtomicAdd(base + 0 * DOUT, acc[i][j][0]);
            unsafeAtomicAdd(base + 1 * DOUT, acc[i][j][1]);
            unsafeAtomicAdd(base + 2 * DOUT, acc[i][j][2]);
            unsafeAtomicAdd(base + 3 * DOUT, acc[i][j][3]);
        }
    }
}

// x_new = relu(xs + C1/rs) -> d_out;  xns = x_new/rs -> ws (fp32)
__global__ void epilogue1_kernel(const float* __restrict__ C1,
                                 const float* __restrict__ xs,
                                 const float* __restrict__ rs,
                                 float* __restrict__ outx,
                                 float* __restrict__ xns) {
    int idx = blockIdx.x * blockDim.x + threadIdx.x;
    if (idx >= NS * DOUT) return;
    int row = idx >> 7;
    float r = rs[row];
    float v = xs[idx] + C1[idx] / r;
    v = v > 0.f ? v : 0.f;
    outx[idx] = v;
    xns[idx] = v / r;
}

// y_new = relu(ys + C2/rt) -> d_out + NS*DOUT
__global__ void epilogue2_kernel(const float* __restrict__ C2,
                                 const float* __restrict__ ys,
                                 const float* __restrict__ rt,
                                 float* __restrict__ outy) {
    int idx = blockIdx.x * blockDim.x + threadIdx.x;
    if (idx >= NT * DOUT) return;
    int row = idx >> 7;
    float v = ys[idx] + C2[idx] / rt[row];
    v = v > 0.f ? v : 0.f;
    outy[idx] = v;
}

extern "C" void kernel_launch(void* const* d_in, const int* in_sizes, int n_in,
                              void* d_out, int out_size, void* d_ws, size_t ws_size,
                              hipStream_t stream) {
    const float* inp_s = (const float*)d_in[0];
    const float* inp_t = (const float*)d_in[1];
    const float* adj   = (const float*)d_in[2];
    const float* adj_s = (const float*)d_in[3];
    const float* adj_t = (const float*)d_in[4];
    const float* W     = (const float*)d_in[5];
    float* out = (float*)d_out;
    float* ws  = (float*)d_ws;

    float* rs  = ws + OFF_RS;
    float* rt  = ws + OFF_RT;
    float* C1  = ws + OFF_C1;
    float* C2  = ws + OFF_C2;
    float* xs  = ws + OFF_XS;
    float* ys  = ws + OFF_YS;
    float* xns = ws + OFF_XNS;
    ushort* xsT = (ushort*)(ws + OFF_XST);
    ushort* ysT = (ushort*)(ws + OFF_YST);

    // zero deg_s + deg_t + C1 + C2 (contiguous [0, OFF_XS))
    zero_kernel<<<1024, 256, 0, stream>>>(ws, OFF_XS / 4);

    // Degree pass, ordered for LLC residency in the GEMM phase:
    // stream adj_t (268 MB) FIRST so adj (134 MB) + adj_s (67 MB) stay resident.
    colsum_t_kernel<<<dim3(NT / 1024, NT / 64), 256, 0, stream>>>(adj_t, rt);
    adj_deg_kernel<<<dim3(NT / 1024, NS / 32), 256, 0, stream>>>(adj, rs, rt);
    rowsum_s_kernel<<<NS / 4, 256, 0, stream>>>(adj_s, rs);
    finish_deg_kernel<<<(NS + NT) / 256, 256, 0, stream>>>(rs);   // rs|rt contiguous

    // projections: xs = (inp_s@W)/rs (fp32) + xsT (bf16 transposed); same for ys
    proj_scale_kernel<<<NS / 64, 256, 0, stream>>>(inp_s, W, rs, xs, xsT, NS);
    proj_scale_kernel<<<NT / 64, 256, 0, stream>>>(inp_t, W, rt, ys, ysT, NT);

    // GEMMs ordered LLC-warm first, adj_t (cold, 268 MB) last.
    // C1 = adj_s@xs + adj@ys   [NS,128]
    gemm_mfma_kernel<0, 1><<<dim3(NS / 128, 8), 256, 0, stream>>>(adj_s, NS, nullptr, xsT, NS, C1, NS / 8);
    gemm_mfma_kernel<0, 1><<<dim3(NS / 128, 8), 256, 0, stream>>>(adj, NT, nullptr, ysT, NT, C1, NT / 8);
    epilogue1_kernel<<<(NS * DOUT) / 256, 256, 0, stream>>>(C1, xs, rs, out, xns);

    // C2 = adj^T@xns + adj_t@ys   [NT,128]
    gemm_mfma_kernel<1, 0><<<dim3(NT / 128, 8), 256, 0, stream>>>(adj, NT, xns, nullptr, 0, C2, NS / 8);
    gemm_mfma_kernel<0, 1><<<dim3(NT / 128, 8), 256, 0, stream>>>(adj_t, NT, nullptr, ysT, NT, C2, NT / 8);
    epilogue2_kernel<<<(NT * DOUT) / 256, 256, 0, stream>>>(C2, ys, rt, out + NS * DOUT);
}